// Round 1
// baseline (148.707 us; speedup 1.0000x reference)
//
#include <hip/hip_runtime.h>
#include <math.h>

#define DD 1024
#define TT 4096
#define BB 16
#define KK 4
#define CC 1000
#define TEMP_F 0.07f
#define EPS_F 1e-6f

__device__ __forceinline__ float blockReduceSum(float v, float* red) {
    int tid = threadIdx.x;
    red[tid] = v; __syncthreads();
    for (int s = 128; s > 0; s >>= 1) {
        if (tid < s) red[tid] += red[tid + s];
        __syncthreads();
    }
    float r = red[0]; __syncthreads();
    return r;
}

__device__ __forceinline__ float blockReduceMax(float v, float* red) {
    int tid = threadIdx.x;
    red[tid] = v; __syncthreads();
    for (int s = 128; s > 0; s >>= 1) {
        if (tid < s) red[tid] = fmaxf(red[tid], red[tid + s]);
        __syncthreads();
    }
    float r = red[0]; __syncthreads();
    return r;
}

// Kernel 1: u_k = normalize(v_k * sigmoid(m_k)); G[j][k] = u_j . u_k  (j<k)
__global__ __launch_bounds__(256) void k_u_g(const float* __restrict__ v,
                                             const float* __restrict__ m,
                                             float* __restrict__ u_ws,
                                             float* __restrict__ G_ws) {
    __shared__ float u_lds[KK * DD];
    __shared__ float red[256];
    int tid = threadIdx.x;
    for (int k = 0; k < KK; ++k) {
        float ss = 0.f;
        for (int d = tid; d < DD; d += 256) {
            float mv = m[k * DD + d];
            float s = v[k * DD + d] * (1.f / (1.f + expf(-mv)));
            u_lds[k * DD + d] = s;
            ss += s * s;
        }
        __syncthreads();
        float tot = blockReduceSum(ss, red);
        float inv = 1.f / (sqrtf(tot) + EPS_F);
        for (int d = tid; d < DD; d += 256) {
            float uu = u_lds[k * DD + d] * inv;
            u_lds[k * DD + d] = uu;
            u_ws[k * DD + d] = uu;
        }
        __syncthreads();
    }
    for (int j = 0; j < KK; ++j) {
        for (int k = j + 1; k < KK; ++k) {
            float p = 0.f;
            for (int d = tid; d < DD; d += 256) p += u_lds[j * DD + d] * u_lds[k * DD + d];
            float tot = blockReduceSum(p, red);
            if (tid == 0) G_ws[j * KK + k] = tot;
        }
    }
}

// Kernel 2: c0[b,t,k] = E[b,t,:] . u_k  — one token per wave, float4 loads.
__global__ __launch_bounds__(256) void k_proj(const float* __restrict__ E,
                                              const float* __restrict__ u_ws,
                                              float* __restrict__ c0) {
    __shared__ float u_lds[KK * DD];
    int tid = threadIdx.x;
    for (int i = tid * 4; i < KK * DD; i += 256 * 4) {
        *reinterpret_cast<float4*>(u_lds + i) = *reinterpret_cast<const float4*>(u_ws + i);
    }
    __syncthreads();
    int wave = tid >> 6, lane = tid & 63;
    size_t g = (size_t)blockIdx.x * 4 + wave;  // token id in [0, B*T)
    const float* e = E + g * DD;
    float acc0 = 0.f, acc1 = 0.f, acc2 = 0.f, acc3 = 0.f;
#pragma unroll
    for (int j = 0; j < 4; ++j) {
        int d = lane * 4 + j * 256;
        float4 ev = *reinterpret_cast<const float4*>(e + d);
        float4 u0 = *reinterpret_cast<const float4*>(u_lds + 0 * DD + d);
        float4 u1 = *reinterpret_cast<const float4*>(u_lds + 1 * DD + d);
        float4 u2 = *reinterpret_cast<const float4*>(u_lds + 2 * DD + d);
        float4 u3 = *reinterpret_cast<const float4*>(u_lds + 3 * DD + d);
        acc0 += ev.x * u0.x + ev.y * u0.y + ev.z * u0.z + ev.w * u0.w;
        acc1 += ev.x * u1.x + ev.y * u1.y + ev.z * u1.z + ev.w * u1.w;
        acc2 += ev.x * u2.x + ev.y * u2.y + ev.z * u2.z + ev.w * u2.w;
        acc3 += ev.x * u3.x + ev.y * u3.y + ev.z * u3.z + ev.w * u3.w;
    }
#pragma unroll
    for (int off = 32; off > 0; off >>= 1) {
        acc0 += __shfl_xor(acc0, off);
        acc1 += __shfl_xor(acc1, off);
        acc2 += __shfl_xor(acc2, off);
        acc3 += __shfl_xor(acc3, off);
    }
    if (lane == 0) {
        float4 o = make_float4(acc0, acc1, acc2, acc3);
        *reinterpret_cast<float4*>(c0 + g * 4) = o;
    }
}

// Kernel 3: per batch row — peel recurrence, softmax stats, top-8 sum -> c_k[b]
__global__ __launch_bounds__(256) void k_peel(const float* __restrict__ c0,
                                              const float* __restrict__ G_ws,
                                              const float* __restrict__ beta,
                                              float* __restrict__ cscal) {
    __shared__ float co[KK * TT];  // 64 KB
    __shared__ float red[256];
    __shared__ float redv[256];
    __shared__ int redi[256];
    int tid = threadIdx.x;
    int b = blockIdx.x;
    float g01 = G_ws[0 * KK + 1], g02 = G_ws[0 * KK + 2], g03 = G_ws[0 * KK + 3];
    float g12 = G_ws[1 * KK + 2], g13 = G_ws[1 * KK + 3], g23 = G_ws[2 * KK + 3];
    float b0 = beta[0], b1 = beta[1], b2 = beta[2];
    float mx[KK];
#pragma unroll
    for (int k = 0; k < KK; ++k) mx[k] = -INFINITY;
    for (int t = tid; t < TT; t += 256) {
        float4 cv = *reinterpret_cast<const float4*>(c0 + ((size_t)b * TT + t) * 4);
        float f0 = cv.x;
        float f1 = cv.y - b0 * g01 * f0;
        float f2 = cv.z - b0 * g02 * f0 - b1 * g12 * f1;
        float f3 = cv.w - b0 * g03 * f0 - b1 * g13 * f1 - b2 * g23 * f2;
        co[0 * TT + t] = f0; co[1 * TT + t] = f1;
        co[2 * TT + t] = f2; co[3 * TT + t] = f3;
        mx[0] = fmaxf(mx[0], f0); mx[1] = fmaxf(mx[1], f1);
        mx[2] = fmaxf(mx[2], f2); mx[3] = fmaxf(mx[3], f3);
    }
    __syncthreads();
    const float invT = 1.f / TEMP_F;
#pragma unroll
    for (int k = 0; k < KK; ++k) {
        float m = blockReduceMax(mx[k], red);
        float se = 0.f, sce = 0.f;
        for (int t = tid; t < TT; t += 256) {
            float x = co[k * TT + t];
            float e = expf((x - m) * invT);
            se += e; sce += x * e;
        }
        se = blockReduceSum(se, red);
        sce = blockReduceSum(sce, red);
        float zsoft = sce / se;
        // top-8 sum via repeated argmax
        float sumtop = 0.f;
        for (int it = 0; it < 8; ++it) {
            float bv = -INFINITY; int bi = 0;
            for (int t = tid; t < TT; t += 256) {
                float x = co[k * TT + t];
                if (x > bv) { bv = x; bi = t; }
            }
            redv[tid] = bv; redi[tid] = bi; __syncthreads();
            for (int s = 128; s > 0; s >>= 1) {
                if (tid < s) {
                    if (redv[tid + s] > redv[tid]) {
                        redv[tid] = redv[tid + s]; redi[tid] = redi[tid + s];
                    }
                }
                __syncthreads();
            }
            float val = redv[0]; int idx = redi[0];
            __syncthreads();
            sumtop += val;
            if (tid == 0) co[k * TT + idx] = -INFINITY;
            __syncthreads();
        }
        if (tid == 0) cscal[b * KK + k] = 0.5f * (sumtop + zsoft);
    }
}

// Kernel 4+5: w_k[c] = cls_W[k,c,:].u_k ; out[b,c] = sum_k alpha_k*(c_k[b]*w_k[c] + bias[k,c])
__global__ __launch_bounds__(256) void k_logits(const float* __restrict__ W,
                                                const float* __restrict__ bias,
                                                const float* __restrict__ alpha,
                                                const float* __restrict__ u_ws,
                                                const float* __restrict__ cscal,
                                                float* __restrict__ out) {
    __shared__ float w_lds[KK];
    int tid = threadIdx.x;
    int c = blockIdx.x;
    int k = tid >> 6, lane = tid & 63;
    const float* wr = W + ((size_t)k * CC + c) * DD;
    const float* ur = u_ws + k * DD;
    float acc = 0.f;
#pragma unroll
    for (int j = 0; j < 4; ++j) {
        int d = lane * 4 + j * 256;
        float4 wv = *reinterpret_cast<const float4*>(wr + d);
        float4 uv = *reinterpret_cast<const float4*>(ur + d);
        acc += wv.x * uv.x + wv.y * uv.y + wv.z * uv.z + wv.w * uv.w;
    }
#pragma unroll
    for (int off = 32; off > 0; off >>= 1) acc += __shfl_xor(acc, off);
    if (lane == 0) w_lds[k] = acc;
    __syncthreads();
    if (tid < BB) {
        int b = tid;
        float s = 0.f;
#pragma unroll
        for (int kk = 0; kk < KK; ++kk)
            s += alpha[kk] * (cscal[b * KK + kk] * w_lds[kk] + bias[kk * CC + c]);
        out[(size_t)b * CC + c] = s;
    }
}

extern "C" void kernel_launch(void* const* d_in, const int* in_sizes, int n_in,
                              void* d_out, int out_size, void* d_ws, size_t ws_size,
                              hipStream_t stream) {
    const float* E     = (const float*)d_in[0];
    const float* v     = (const float*)d_in[1];
    const float* m     = (const float*)d_in[2];
    const float* W     = (const float*)d_in[3];
    const float* cb    = (const float*)d_in[4];
    const float* beta  = (const float*)d_in[5];
    const float* alpha = (const float*)d_in[6];
    float* out = (float*)d_out;
    float* ws = (float*)d_ws;

    float* u_ws  = ws;                          // K*D      = 4096 floats
    float* G_ws  = ws + KK * DD;                // 16 floats
    float* cscal = ws + KK * DD + 16;           // B*K = 64 floats
    float* c0    = ws + KK * DD + 16 + 64;      // B*T*K = 262144 floats (16B-aligned offset)

    k_u_g<<<1, 256, 0, stream>>>(v, m, u_ws, G_ws);
    k_proj<<<(BB * TT) / 4, 256, 0, stream>>>(E, u_ws, c0);
    k_peel<<<BB, 256, 0, stream>>>(c0, G_ws, beta, cscal);
    k_logits<<<CC, 256, 0, stream>>>(W, cb, alpha, u_ws, cscal, out);
}

// Round 2
// 64.871 us; speedup vs baseline: 2.2923x; 2.2923x over previous
//
#include <hip/hip_runtime.h>
#include <math.h>

#define DD 1024
#define TT 4096
#define BB 16
#define KK 4
#define CC 1000
#define TEMP_F 0.07f
#define EPS_F 1e-6f
#define NPROJ 2048  // blocks for the E@U part of the fused kernel

// ---------- sorted-8 register-list helpers (all static indexing) ----------
// compare-exchange: a=max, b=min  (descending order)
#define CE(a, b) { float _mx = fmaxf(a, b), _mn = fminf(a, b); a = _mx; b = _mn; }
// insert y into sorted-desc list s0..s7 (compare-swap chain)
#define INS8(y_) { float y = (y_); \
    CE(s0, y) CE(s1, y) CE(s2, y) CE(s3, y) CE(s4, y) CE(s5, y) CE(s6, y) CE(s7, y) }
// resort a bitonic 8-sequence into descending order (3 bitonic-merge stages)
#define RESORT8() { \
    CE(s0, s4) CE(s1, s5) CE(s2, s6) CE(s3, s7) \
    CE(s0, s2) CE(s1, s3) CE(s4, s6) CE(s5, s7) \
    CE(s0, s1) CE(s2, s3) CE(s4, s5) CE(s6, s7) }
// merge with partner lane's sorted-desc list: top-8 of union = max(a_i, b_{7-i}),
// result is bitonic -> resort. Both partners compute the same set.
#define WMERGE(off) { \
    float t0 = __shfl_xor(s0, off), t1 = __shfl_xor(s1, off), \
          t2 = __shfl_xor(s2, off), t3 = __shfl_xor(s3, off), \
          t4 = __shfl_xor(s4, off), t5 = __shfl_xor(s5, off), \
          t6 = __shfl_xor(s6, off), t7 = __shfl_xor(s7, off); \
    s0 = fmaxf(s0, t7); s1 = fmaxf(s1, t6); s2 = fmaxf(s2, t5); s3 = fmaxf(s3, t4); \
    s4 = fmaxf(s4, t3); s5 = fmaxf(s5, t2); s6 = fmaxf(s6, t1); s7 = fmaxf(s7, t0); \
    RESORT8() }
// merge sorted-desc regs with sorted-desc 8-array in LDS (static reversed idx)
#define LMERGE(L) { \
    s0 = fmaxf(s0, (L)[7]); s1 = fmaxf(s1, (L)[6]); s2 = fmaxf(s2, (L)[5]); \
    s3 = fmaxf(s3, (L)[4]); s4 = fmaxf(s4, (L)[3]); s5 = fmaxf(s5, (L)[2]); \
    s6 = fmaxf(s6, (L)[1]); s7 = fmaxf(s7, (L)[0]); \
    RESORT8() }

// Kernel 1: u_k = normalize(v_k * sigmoid(m_k)) (one wave per k, parallel);
// Gram G[j][k] = u_j . u_k distributed over waves.
__global__ __launch_bounds__(256) void k_u_g(const float* __restrict__ v,
                                             const float* __restrict__ m,
                                             float* __restrict__ u_ws,
                                             float* __restrict__ G_ws) {
    __shared__ float u_lds[KK * DD];
    int tid = threadIdx.x, w = tid >> 6, lane = tid & 63;
    float s_reg[16];
    float ss = 0.f;
#pragma unroll
    for (int i = 0; i < 16; ++i) {
        int d = lane + i * 64;
        float mv = m[w * DD + d];
        float s = v[w * DD + d] * (1.f / (1.f + expf(-mv)));
        s_reg[i] = s; ss += s * s;
    }
#pragma unroll
    for (int off = 32; off; off >>= 1) ss += __shfl_xor(ss, off);
    float inv = 1.f / (sqrtf(ss) + EPS_F);
#pragma unroll
    for (int i = 0; i < 16; ++i) {
        int d = lane + i * 64;
        float uu = s_reg[i] * inv;
        u_lds[w * DD + d] = uu;
        u_ws[w * DD + d] = uu;
    }
    __syncthreads();
    // 6 pairs distributed over 4 waves: p -> (j,k)
    for (int p = w; p < 6; p += 4) {
        int j = (p < 3) ? 0 : ((p < 5) ? 1 : 2);
        int k = (p < 3) ? (p + 1) : ((p < 5) ? (p - 1) : 3);
        float acc = 0.f;
#pragma unroll
        for (int i = 0; i < 16; ++i) {
            int d = lane + i * 64;
            acc += u_lds[j * DD + d] * u_lds[k * DD + d];
        }
#pragma unroll
        for (int off = 32; off; off >>= 1) acc += __shfl_xor(acc, off);
        if (lane == 0) G_ws[j * KK + k] = acc;
    }
}

// Kernel 2 (fused): blocks [0,NPROJ): c0[b,t,k] = E[b,t,:].u_k  (u held in VGPRs)
//                   blocks [NPROJ,NPROJ+CC): wdot[k][c] = cls_W[k,c,:].u_k
__global__ __launch_bounds__(256) void k_proj_wu(const float* __restrict__ E,
                                                 const float* __restrict__ W,
                                                 const float* __restrict__ u_ws,
                                                 float* __restrict__ c0,
                                                 float* __restrict__ wdot) {
    int tid = threadIdx.x, w = tid >> 6, lane = tid & 63;
    if (blockIdx.x < NPROJ) {
        float4 U[KK][4];
#pragma unroll
        for (int k = 0; k < KK; ++k)
#pragma unroll
            for (int j = 0; j < 4; ++j)
                U[k][j] = *reinterpret_cast<const float4*>(u_ws + k * DD + lane * 4 + j * 256);
        const int ITERS = (BB * TT) / (NPROJ * 4);  // 8
#pragma unroll 1
        for (int it = 0; it < ITERS; ++it) {
            size_t g = (size_t)(blockIdx.x * 4 + w) + (size_t)it * (NPROJ * 4);
            const float* e = E + g * DD;
            float a0 = 0.f, a1 = 0.f, a2 = 0.f, a3 = 0.f;
#pragma unroll
            for (int j = 0; j < 4; ++j) {
                float4 ev = *reinterpret_cast<const float4*>(e + lane * 4 + j * 256);
                a0 += ev.x * U[0][j].x + ev.y * U[0][j].y + ev.z * U[0][j].z + ev.w * U[0][j].w;
                a1 += ev.x * U[1][j].x + ev.y * U[1][j].y + ev.z * U[1][j].z + ev.w * U[1][j].w;
                a2 += ev.x * U[2][j].x + ev.y * U[2][j].y + ev.z * U[2][j].z + ev.w * U[2][j].w;
                a3 += ev.x * U[3][j].x + ev.y * U[3][j].y + ev.z * U[3][j].z + ev.w * U[3][j].w;
            }
#pragma unroll
            for (int off = 32; off; off >>= 1) {
                a0 += __shfl_xor(a0, off);
                a1 += __shfl_xor(a1, off);
                a2 += __shfl_xor(a2, off);
                a3 += __shfl_xor(a3, off);
            }
            if (lane == 0)
                *reinterpret_cast<float4*>(c0 + g * 4) = make_float4(a0, a1, a2, a3);
        }
    } else {
        int c = blockIdx.x - NPROJ;
        const float* wr = W + ((size_t)w * CC + c) * DD;
        const float* ur = u_ws + w * DD;
        float acc = 0.f;
#pragma unroll
        for (int j = 0; j < 4; ++j) {
            float4 wv = *reinterpret_cast<const float4*>(wr + lane * 4 + j * 256);
            float4 uv = *reinterpret_cast<const float4*>(ur + lane * 4 + j * 256);
            acc += wv.x * uv.x + wv.y * uv.y + wv.z * uv.z + wv.w * uv.w;
        }
#pragma unroll
        for (int off = 32; off; off >>= 1) acc += __shfl_xor(acc, off);
        if (lane == 0) wdot[w * CC + c] = acc;
    }
}

// Kernel 3: one block per (b,k): recompute peel recurrence per token (local),
// softmax stats + single-pass top-8 -> cscal[b,k] = 0.5*(sum_top8 + z_soft)
__global__ __launch_bounds__(256) void k_peel2(const float* __restrict__ c0,
                                               const float* __restrict__ G_ws,
                                               const float* __restrict__ beta,
                                               float* __restrict__ cscal) {
    __shared__ float redm[4], reds[4], redc[4];
    __shared__ float topl[4][8];
    int tid = threadIdx.x, w = tid >> 6, lane = tid & 63;
    int b = blockIdx.x >> 2, k = blockIdx.x & 3;
    float g01 = G_ws[0 * KK + 1], g02 = G_ws[0 * KK + 2], g03 = G_ws[0 * KK + 3];
    float g12 = G_ws[1 * KK + 2], g13 = G_ws[1 * KK + 3], g23 = G_ws[2 * KK + 3];
    float b0 = beta[0], b1 = beta[1], b2 = beta[2];
    float fk[16];
    float mx = -INFINITY;
#pragma unroll
    for (int i = 0; i < 16; ++i) {
        int t = tid + i * 256;
        float4 cv = *reinterpret_cast<const float4*>(c0 + ((size_t)b * TT + t) * 4);
        float f0 = cv.x;
        float f1 = cv.y - b0 * g01 * f0;
        float f2 = cv.z - b0 * g02 * f0 - b1 * g12 * f1;
        float f3 = cv.w - b0 * g03 * f0 - b1 * g13 * f1 - b2 * g23 * f2;
        float f = (k == 0) ? f0 : ((k == 1) ? f1 : ((k == 2) ? f2 : f3));
        fk[i] = f; mx = fmaxf(mx, f);
    }
#pragma unroll
    for (int off = 32; off; off >>= 1) mx = fmaxf(mx, __shfl_xor(mx, off));
    if (lane == 0) redm[w] = mx;
    __syncthreads();
    mx = fmaxf(fmaxf(redm[0], redm[1]), fmaxf(redm[2], redm[3]));
    const float invT = 1.f / TEMP_F;
    float se = 0.f, sce = 0.f;
#pragma unroll
    for (int i = 0; i < 16; ++i) {
        float e = expf((fk[i] - mx) * invT);
        se += e; sce += fk[i] * e;
    }
#pragma unroll
    for (int off = 32; off; off >>= 1) {
        se += __shfl_xor(se, off);
        sce += __shfl_xor(sce, off);
    }
    if (lane == 0) { reds[w] = se; redc[w] = sce; }
    __syncthreads();
    se = reds[0] + reds[1] + reds[2] + reds[3];
    sce = redc[0] + redc[1] + redc[2] + redc[3];
    float zsoft = sce / se;
    // single-pass top-8: per-thread sorted-8 -> wave bitonic merge -> 4-list merge
    float s0 = -INFINITY, s1 = -INFINITY, s2 = -INFINITY, s3 = -INFINITY,
          s4 = -INFINITY, s5 = -INFINITY, s6 = -INFINITY, s7 = -INFINITY;
#pragma unroll
    for (int i = 0; i < 16; ++i) INS8(fk[i]);
    WMERGE(1) WMERGE(2) WMERGE(4) WMERGE(8) WMERGE(16) WMERGE(32)
    if (lane == 0) {
        topl[w][0] = s0; topl[w][1] = s1; topl[w][2] = s2; topl[w][3] = s3;
        topl[w][4] = s4; topl[w][5] = s5; topl[w][6] = s6; topl[w][7] = s7;
    }
    __syncthreads();
    if (tid == 0) {
        LMERGE(topl[1]) LMERGE(topl[2]) LMERGE(topl[3])
        float sumtop = s0 + s1 + s2 + s3 + s4 + s5 + s6 + s7;
        cscal[b * KK + k] = 0.5f * (sumtop + zsoft);
    }
}

// Kernel 4: out[b,c] = sum_k alpha_k * (cscal[b,k]*wdot[k,c] + bias[k,c])
__global__ __launch_bounds__(256) void k_out(const float* __restrict__ wdot,
                                             const float* __restrict__ bias,
                                             const float* __restrict__ alpha,
                                             const float* __restrict__ cscal,
                                             float* __restrict__ out) {
    int idx = blockIdx.x * 256 + threadIdx.x;
    if (idx >= BB * CC) return;
    int b = idx / CC, c = idx % CC;
    float s = 0.f;
#pragma unroll
    for (int k = 0; k < KK; ++k)
        s += alpha[k] * (cscal[b * KK + k] * wdot[k * CC + c] + bias[k * CC + c]);
    out[idx] = s;
}

extern "C" void kernel_launch(void* const* d_in, const int* in_sizes, int n_in,
                              void* d_out, int out_size, void* d_ws, size_t ws_size,
                              hipStream_t stream) {
    const float* E     = (const float*)d_in[0];
    const float* v     = (const float*)d_in[1];
    const float* m     = (const float*)d_in[2];
    const float* W     = (const float*)d_in[3];
    const float* cb    = (const float*)d_in[4];
    const float* beta  = (const float*)d_in[5];
    const float* alpha = (const float*)d_in[6];
    float* out = (float*)d_out;
    float* ws = (float*)d_ws;

    float* u_ws  = ws;                     // 4096 floats
    float* G_ws  = ws + 4096;              // 16
    float* cscal = ws + 4112;              // 64
    float* wdot  = ws + 4176;              // 4000
    float* c0    = ws + 8176;              // B*T*K = 262144 (byte off 32704, 16B-aligned)

    k_u_g<<<1, 256, 0, stream>>>(v, m, u_ws, G_ws);
    k_proj_wu<<<NPROJ + CC, 256, 0, stream>>>(E, W, u_ws, c0, wdot);
    k_peel2<<<BB * KK, 256, 0, stream>>>(c0, G_ws, beta, cscal);
    k_out<<<(BB * CC + 255) / 256, 256, 0, stream>>>(wdot, cb, alpha, cscal, out);
}